// Round 3
// baseline (970.792 us; speedup 1.0000x reference)
//
#include <hip/hip_runtime.h>
#include <hip/hip_bf16.h>

#define HID 256
#define NH 4
#define DH 64

typedef __attribute__((ext_vector_type(8))) short bf16x8;
typedef __attribute__((ext_vector_type(4))) short bf16x4;
typedef __attribute__((ext_vector_type(4))) float f32x4;

#define MFMA16(a, b, c) __builtin_amdgcn_mfma_f32_16x16x32_bf16((a), (b), (c), 0, 0, 0)

// K=16 MFMA via asm (gfx950-listed mnemonic, cdna4_isa.md §10).
// A[m=lane&15][k=(lane>>4)*4+j], B[n=lane&15][k same], D[row=(lane>>4)*4+r][col=lane&15].
__device__ __forceinline__ f32x4 mfma16k(bf16x4 a, bf16x4 b, f32x4 c) {
  asm("v_mfma_f32_16x16x16_bf16 %0, %1, %2, %0" : "+v"(c) : "v"(a), "v"(b));
  return c;
}

// LDS row strides (bf16 elems); 16B-aligned rows, 2-way max bank aliasing (free, m136)
#define LQK 72
#define LVT 136

__device__ __forceinline__ short f2bf(float f) {       // RNE fp32->bf16 (finite inputs)
  unsigned u = __float_as_uint(f);
  unsigned r = (u + 0x7fffu + ((u >> 16) & 1u)) >> 16;
  return (short)r;
}

__device__ __forceinline__ bf16x8 ld_cvt8(const float* p) {  // 8 fp32 -> bf16x8
  float4 a = *(const float4*)p;
  float4 b = *(const float4*)(p + 4);
  bf16x8 r;
  r[0] = f2bf(a.x); r[1] = f2bf(a.y); r[2] = f2bf(a.z); r[3] = f2bf(a.w);
  r[4] = f2bf(b.x); r[5] = f2bf(b.y); r[6] = f2bf(b.z); r[7] = f2bf(b.w);
  return r;
}

// One-shot weight conversion: Wq,Wk,Wv,Wo fp32 -> bf16 into ws (4 x 256x256 = 512KB).
__global__ __launch_bounds__(256) void cvt_w_kernel(
    const float* __restrict__ Wq, const float* __restrict__ Wk,
    const float* __restrict__ Wv, const float* __restrict__ Wo,
    short* __restrict__ Wb)
{
  const int i = (blockIdx.x * 256 + threadIdx.x) * 4;   // 64 blocks cover 65536 elems
  const float* src[4] = {Wq, Wk, Wv, Wo};
  #pragma unroll
  for (int m = 0; m < 4; m++) {
    float4 v = *(const float4*)(src[m] + i);
    short4 r;
    r.x = f2bf(v.x); r.y = f2bf(v.y); r.z = f2bf(v.z); r.w = f2bf(v.w);
    *(short4*)(Wb + m * (HID * HID) + i) = r;
  }
}

// One-shot msg conversion fp32 -> bf16 (kills 4x-redundant per-head cvt in attn).
__global__ __launch_bounds__(256) void cvt_msg_kernel(
    const float* __restrict__ src, short* __restrict__ dst, int n8)
{
  int i = blockIdx.x * 256 + threadIdx.x;
  const int stride = gridDim.x * 256;
  for (; i < n8; i += stride)
    *(bf16x8*)(dst + (size_t)i * 8) = ld_cvt8(src + (size_t)i * 8);
}

// One block per (molecule, head); 4 waves, wave owns q-tiles {wave, wave+4}.
// Swapped-operand scheme (no P/Q LDS round-trips):
//   Q^T = mfma(Wq, X)  -> lane(c,g) reg r holds Q[q=c][f=nt*16+g*4+r]  == B-frag k-quads
//   S^T = mfma16k(K, Q) -> lane(c,g) reg r holds S[q=c][key=nt*16+g*4+r]
//   softmax lane-local over (nt,r) + 2 shfl across g; P packs directly into
//   the 16x16x16 A-frag for PV. K_s/V_t stay in LDS as MFMA operand sources.
template<bool XB>
__global__ __launch_bounds__(256, 4) void attn_kernel(
    const void* __restrict__ xsrc, const short* __restrict__ Wb,
    const int* __restrict__ starts, const int* __restrict__ sizes,
    short* __restrict__ O)
{
  __shared__ __align__(16) short K_s[128 * LQK];      // K rows (QK^T A-operand source)
  __shared__ __align__(16) short V_t[DH * LVT];       // V^T rows (PV B-operand source)

  // XCD swizzle: put the 4 head-blocks of a molecule on one XCD (bid%8 round-robin)
  const int b = blockIdx.x;
  int mol, head;
  if ((gridDim.x & 31) == 0) { mol = (b & 7) + ((b >> 5) << 3); head = (b >> 3) & 3; }
  else                       { mol = b >> 2;  head = b & 3; }

  const int L     = sizes[mol];
  const int start = starts[mol];
  const int Mt    = (L + 15) >> 4;      // 16-row q/key tiles (2..8)

  const int tid  = threadIdx.x;
  const int wave = tid >> 6;
  const int lane = tid & 63;
  const int c = lane & 15;              // n/m index within tile
  const int g = lane >> 4;              // k-quad / row-quad

  bf16x4 qb[2][4];                      // Q B-frags (scale pre-folded), per owned q-tile

  // ================= Phase 1: QKV projection (MFMA) =================
  const bf16x8 zf = {0, 0, 0, 0, 0, 0, 0, 0};
  #pragma unroll
  for (int i = 0; i < 2; i++) {
    const int mt = wave + 4 * i;
    if (mt >= Mt) break;

    bf16x8 a[8];                        // X tile frags (A for K/V proj, B for Q^T proj)
    {
      int rl = mt * 16 + c;
      bool v = rl < L;
      if constexpr (XB) {
        const short* xp = (const short*)xsrc + (size_t)(start + (v ? rl : 0)) * HID + g * 8;
        #pragma unroll
        for (int ks = 0; ks < 8; ks++) { bf16x8 t = *(const bf16x8*)(xp + ks * 32); a[ks] = v ? t : zf; }
      } else {
        const float* xp = (const float*)xsrc + (size_t)(start + (v ? rl : 0)) * HID + g * 8;
        #pragma unroll
        for (int ks = 0; ks < 8; ks++) { bf16x8 t = ld_cvt8(xp + ks * 32); a[ks] = v ? t : zf; }
      }
    }

    #pragma unroll
    for (int nt = 0; nt < 12; nt++) {   // 192 output cols: q(0-3) k(4-7) v(8-11)
      const short* Wp = Wb + (nt >> 2) * (HID * HID)
                      + (size_t)(head * 64 + (nt & 3) * 16 + c) * HID + g * 8;
      bf16x8 bw[8];
      #pragma unroll
      for (int ks = 0; ks < 8; ks++) bw[ks] = *(const bf16x8*)(Wp + ks * 32);

      f32x4 acc = {0.f, 0.f, 0.f, 0.f};
      if (nt < 4) {                     // Q^T: swap operands, keep Q in registers
        #pragma unroll
        for (int ks = 0; ks < 8; ks++) acc = MFMA16(bw[ks], a[ks], acc);
        #pragma unroll
        for (int r = 0; r < 4; r++) qb[i][nt][r] = f2bf(acc[r] * 0.125f);  // fold DH^-0.5 (exact pow2)
      } else {
        #pragma unroll
        for (int ks = 0; ks < 8; ks++) acc = MFMA16(a[ks], bw[ks], acc);
        #pragma unroll
        for (int r = 0; r < 4; r++) {
          short val = f2bf(acc[r]);
          int row = mt * 16 + g * 4 + r;                  // < Mt*16 always
          if (nt < 8) K_s[row * LQK + (nt - 4) * 16 + c] = val;            // K row-major
          else        V_t[((nt - 8) * 16 + c) * LVT + row] = val;          // V transposed
        }
      }
    }
  }
  __syncthreads();   // uniform: all K_s / V_t visible

  // ================= Phase 2: attention per owned q-tile =================
  #pragma unroll
  for (int i = 0; i < 2; i++) {
    const int mt = wave + 4 * i;
    if (mt >= Mt) continue;

    // ---- S^T = K Q^T: lane(c,g) reg r = S[q=c][key=nt*16+g*4+r] ----
    float sv[8][4];
    #pragma unroll
    for (int nt = 0; nt < 8; nt++) {
      if (nt < Mt) {
        f32x4 acc = {0.f, 0.f, 0.f, 0.f};
        #pragma unroll
        for (int ks = 0; ks < 4; ks++) {
          bf16x4 kb = *(const bf16x4*)&K_s[(nt * 16 + c) * LQK + ks * 16 + g * 4];
          acc = mfma16k(kb, qb[i][ks], acc);
        }
        sv[nt][0] = acc[0]; sv[nt][1] = acc[1]; sv[nt][2] = acc[2]; sv[nt][3] = acc[3];
      }
    }

    // ---- softmax: keys lane-local (nt,r), queries per-lane; cross-g via 2 shfl ----
    float mr = -3.0e38f;
    #pragma unroll
    for (int nt = 0; nt < 8; nt++) {
      if (nt < Mt) {
        #pragma unroll
        for (int r = 0; r < 4; r++) {
          int key = nt * 16 + g * 4 + r;
          float v = (key < L) ? sv[nt][r] : -3.0e38f;
          sv[nt][r] = v;
          mr = fmaxf(mr, v);
        }
      }
    }
    mr = fmaxf(mr, __shfl_xor(mr, 16));
    mr = fmaxf(mr, __shfl_xor(mr, 32));
    float sum = 0.f;
    #pragma unroll
    for (int nt = 0; nt < 8; nt++) {
      if (nt < Mt) {
        #pragma unroll
        for (int r = 0; r < 4; r++) {
          float e = (sv[nt][r] > -1.0e37f) ? __expf(sv[nt][r] - mr) : 0.f;
          sv[nt][r] = e;
          sum += e;
        }
      }
    }
    sum += __shfl_xor(sum, 16);
    sum += __shfl_xor(sum, 32);
    float inv = 1.f / sum;

    bf16x4 pa[8];                       // P A-frags: direct, no cross-lane movement
    #pragma unroll
    for (int nt = 0; nt < 8; nt++) {
      if (nt < Mt) {
        #pragma unroll
        for (int r = 0; r < 4; r++) pa[nt][r] = f2bf(sv[nt][r] * inv);
      }
    }

    // ---- O = P V, ReLU, store bf16 to ws ----
    #pragma unroll
    for (int nt2 = 0; nt2 < 4; nt2++) {
      f32x4 acc = {0.f, 0.f, 0.f, 0.f};
      #pragma unroll
      for (int nt = 0; nt < 8; nt++) {
        if (nt < Mt) {
          bf16x4 vb = *(const bf16x4*)&V_t[(nt2 * 16 + c) * LVT + nt * 16 + g * 4];
          acc = mfma16k(pa[nt], vb, acc);
        }
      }
      #pragma unroll
      for (int r = 0; r < 4; r++) {
        int rl = mt * 16 + g * 4 + r;
        if (rl < L)
          O[(size_t)(start + rl) * HID + head * 64 + nt2 * 16 + c] =
              f2bf(fmaxf(acc[r], 0.f));
      }
    }
  }
}

// MFMA out-projection + bias + LayerNorm. Block = 32 rows, wave owns 64 cols.
__global__ __launch_bounds__(256) void proj_ln_kernel(
    const short* __restrict__ Ob, const short* __restrict__ Wob,
    const float* __restrict__ bo, const float* __restrict__ gamma,
    const float* __restrict__ beta, float* __restrict__ out, int total)
{
  __shared__ __align__(16) float o_s[32 * 260];   // 33.3 KB, stride 260 (1040B, 16B-aligned)
  const int base = blockIdx.x * 32;
  const int tid  = threadIdx.x;
  const int wave = tid >> 6;
  const int lane = tid & 63;
  const int c = lane & 15, g = lane >> 4;

  // A-frags from O (already bf16)
  bf16x8 a[2][8];
  #pragma unroll
  for (int i = 0; i < 2; i++) {
    int row = base + i * 16 + c;
    if (row >= total) row = total - 1;
    const short* p = Ob + (size_t)row * HID + g * 8;
    #pragma unroll
    for (int ks = 0; ks < 8; ks++) a[i][ks] = *(const bf16x8*)(p + ks * 32);
  }

  #pragma unroll
  for (int nt = 0; nt < 4; nt++) {
    const short* Wp = Wob + (size_t)(wave * 64 + nt * 16 + c) * HID + g * 8;
    bf16x8 b[8];
    #pragma unroll
    for (int ks = 0; ks < 8; ks++) b[ks] = *(const bf16x8*)(Wp + ks * 32);
    #pragma unroll
    for (int i = 0; i < 2; i++) {
      f32x4 acc = {0.f, 0.f, 0.f, 0.f};
      #pragma unroll
      for (int ks = 0; ks < 8; ks++) acc = MFMA16(a[i][ks], b[ks], acc);
      #pragma unroll
      for (int r = 0; r < 4; r++)
        o_s[(i * 16 + g * 4 + r) * 260 + wave * 64 + nt * 16 + c] = acc[r];
    }
  }
  __syncthreads();

  // LayerNorm: wave handles 8 rows; lane covers 4 cols
  float4 bo4 = *(const float4*)(bo + lane * 4);
  float4 g4  = *(const float4*)(gamma + lane * 4);
  float4 b4  = *(const float4*)(beta + lane * 4);
  #pragma unroll
  for (int r8 = 0; r8 < 8; r8++) {
    int rl = wave * 8 + r8;
    float4 o = *(const float4*)&o_s[rl * 260 + lane * 4];
    o.x += bo4.x; o.y += bo4.y; o.z += bo4.z; o.w += bo4.w;
    float s  = o.x + o.y + o.z + o.w;
    float ss = o.x * o.x + o.y * o.y + o.z * o.z + o.w * o.w;
    #pragma unroll
    for (int off = 32; off; off >>= 1) { s += __shfl_xor(s, off); ss += __shfl_xor(ss, off); }
    float mu  = s * (1.f / HID);
    float var = ss * (1.f / HID) - mu * mu;
    float inv = rsqrtf(var + 1e-5f);
    int row = base + rl;
    if (row < total) {
      float4 res;
      res.x = (o.x - mu) * inv * g4.x + b4.x;
      res.y = (o.y - mu) * inv * g4.y + b4.y;
      res.z = (o.z - mu) * inv * g4.z + b4.z;
      res.w = (o.w - mu) * inv * g4.w + b4.w;
      if (row == 0) res = make_float4(0.f, 0.f, 0.f, 0.f);  // cached_zero_vector
      *(float4*)(out + (size_t)row * HID + lane * 4) = res;
    }
  }
}

extern "C" void kernel_launch(void* const* d_in, const int* in_sizes, int n_in,
                              void* d_out, int out_size, void* d_ws, size_t ws_size,
                              hipStream_t stream) {
  const float* msg   = (const float*)d_in[0];
  const float* Wq    = (const float*)d_in[1];
  const float* Wk    = (const float*)d_in[2];
  const float* Wv    = (const float*)d_in[3];
  const float* Wo    = (const float*)d_in[4];
  const float* bo    = (const float*)d_in[5];
  const float* gamma = (const float*)d_in[6];
  const float* beta  = (const float*)d_in[7];
  const int* starts  = (const int*)d_in[8];
  const int* sizes   = (const int*)d_in[9];

  const int nmols = in_sizes[8];
  const int total = in_sizes[0] / HID;

  short* O  = (short*)d_ws;                       // [total][HID] bf16 o_relu scratch (~84 MB)
  short* Wb = O + (size_t)total * HID;            // 4 x 256x256 bf16 weights (+512 KB)
  short* Xb = Wb + 4 * HID * HID;                 // [total][HID] bf16 msg (+~84 MB, if it fits)

  size_t need = ((size_t)total * HID * 2 + 4 * HID * HID) * sizeof(short);
  const bool use_xb = ws_size >= need;

  cvt_w_kernel<<<(HID * HID) / (256 * 4), 256, 0, stream>>>(Wq, Wk, Wv, Wo, Wb);
  if (use_xb) {
    int n8 = total * (HID / 8);
    int gsz = (n8 + 255) / 256; if (gsz > 2048) gsz = 2048;
    cvt_msg_kernel<<<gsz, 256, 0, stream>>>(msg, Xb, n8);
    attn_kernel<true><<<nmols * NH, 256, 0, stream>>>(Xb, Wb, starts, sizes, O);
  } else {
    attn_kernel<false><<<nmols * NH, 256, 0, stream>>>(msg, Wb, starts, sizes, O);
  }
  proj_ln_kernel<<<(total + 31) / 32, 256, 0, stream>>>(
      O, Wb + 3 * HID * HID, bo, gamma, beta, (float*)d_out, total);
}

// Round 4
// 596.547 us; speedup vs baseline: 1.6274x; 1.6274x over previous
//
#include <hip/hip_runtime.h>
#include <hip/hip_bf16.h>

#define HID 256
#define NH 4
#define DH 64

typedef __attribute__((ext_vector_type(8))) short bf16x8;
typedef __attribute__((ext_vector_type(4))) short bf16x4;
typedef __attribute__((ext_vector_type(4))) float f32x4;

#define MFMA16(a, b, c) __builtin_amdgcn_mfma_f32_16x16x32_bf16((a), (b), (c), 0, 0, 0)

// K=16 MFMA via asm (gfx950-listed mnemonic, cdna4_isa.md §10) — verified R3.
// A[m=lane&15][k=(lane>>4)*4+j], B[n=lane&15][k same], D[row=(lane>>4)*4+r][col=lane&15].
__device__ __forceinline__ f32x4 mfma16k(bf16x4 a, bf16x4 b, f32x4 c) {
  asm("v_mfma_f32_16x16x16_bf16 %0, %1, %2, %0" : "+v"(c) : "v"(a), "v"(b));
  return c;
}

// LDS row strides (bf16 elems); 16B-aligned rows, 2-way max bank aliasing (free, m136)
#define LQK 72
#define LVT 136

__device__ __forceinline__ short f2bf(float f) {       // RNE fp32->bf16 (finite inputs)
  unsigned u = __float_as_uint(f);
  unsigned r = (u + 0x7fffu + ((u >> 16) & 1u)) >> 16;
  return (short)r;
}

__device__ __forceinline__ bf16x8 ld_cvt8(const float* p) {  // 8 fp32 -> bf16x8
  float4 a = *(const float4*)p;
  float4 b = *(const float4*)(p + 4);
  bf16x8 r;
  r[0] = f2bf(a.x); r[1] = f2bf(a.y); r[2] = f2bf(a.z); r[3] = f2bf(a.w);
  r[4] = f2bf(b.x); r[5] = f2bf(b.y); r[6] = f2bf(b.z); r[7] = f2bf(b.w);
  return r;
}

// One-shot weight conversion INTO MFMA-FRAG ORDER:
//   Wb[(((mat*4+h)*4+nt)*8+ks)*64 + lane] (bf16x8 chunks)
//   = W_mat[row = h*64 + nt*16 + (lane&15)][col = ks*32 + (lane>>4)*8 .. +8]
// A wave's B-frag load for (mat,h,nt,ks) is then 64 consecutive 16B chunks (1KB,
// 4 cache lines) instead of 16 scattered lines — kills the L1-miss scatter that
// pinned attn at ~600us across R1/R3.
__global__ __launch_bounds__(256) void cvt_w_kernel(
    const float* __restrict__ Wq, const float* __restrict__ Wk,
    const float* __restrict__ Wv, const float* __restrict__ Wo,
    short* __restrict__ Wb)
{
  const int id   = blockIdx.x * 256 + threadIdx.x;   // 32768 ids (128 blocks)
  const int lane = id & 63;
  const int ks   = (id >> 6) & 7;
  const int nt   = (id >> 9) & 3;
  const int h    = (id >> 11) & 3;
  const int mat  = id >> 13;
  const float* src[4] = {Wq, Wk, Wv, Wo};
  const int row = h * 64 + nt * 16 + (lane & 15);
  const int col = ks * 32 + (lane >> 4) * 8;
  *(bf16x8*)(Wb + (size_t)id * 8) = ld_cvt8(src[mat] + row * HID + col);
}

// One-shot msg conversion fp32 -> bf16 (kills 4x-redundant per-head cvt in attn).
__global__ __launch_bounds__(256) void cvt_msg_kernel(
    const float* __restrict__ src, short* __restrict__ dst, int n8)
{
  int i = blockIdx.x * 256 + threadIdx.x;
  const int stride = gridDim.x * 256;
  for (; i < n8; i += stride)
    *(bf16x8*)(dst + (size_t)i * 8) = ld_cvt8(src + (size_t)i * 8);
}

// One block per (molecule, head); 4 waves, wave owns q-tiles {wave, wave+4}.
// Swapped-operand scheme (no P/Q LDS round-trips); weights read from frag-order Wb.
template<bool XB>
__global__ __launch_bounds__(256, 4) void attn_kernel(
    const void* __restrict__ xsrc, const short* __restrict__ Wb,
    const int* __restrict__ starts, const int* __restrict__ sizes,
    short* __restrict__ O)
{
  __shared__ __align__(16) short K_s[128 * LQK];      // K rows (QK^T A-operand source)
  __shared__ __align__(16) short V_t[DH * LVT];       // V^T rows (PV B-operand source)

  // XCD swizzle: put the 4 head-blocks of a molecule on one XCD (bid%8 round-robin)
  const int b = blockIdx.x;
  int mol, head;
  if ((gridDim.x & 31) == 0) { mol = (b & 7) + ((b >> 5) << 3); head = (b >> 3) & 3; }
  else                       { mol = b >> 2;  head = b & 3; }

  const int L     = sizes[mol];
  const int start = starts[mol];
  const int Mt    = (L + 15) >> 4;      // 16-row q/key tiles (2..8)

  const int tid  = threadIdx.x;
  const int wave = tid >> 6;
  const int lane = tid & 63;
  const int c = lane & 15;              // n/m index within tile
  const int g = lane >> 4;              // k-quad / row-quad

  bf16x4 qb[2][4];                      // Q B-frags (scale pre-folded), per owned q-tile

  // ================= Phase 1: QKV projection (MFMA) =================
  const bf16x8 zf = {0, 0, 0, 0, 0, 0, 0, 0};
  #pragma unroll
  for (int i = 0; i < 2; i++) {
    const int mt = wave + 4 * i;
    if (mt >= Mt) break;

    bf16x8 a[8];                        // X tile frags (A for K/V proj, B for Q^T proj)
    {
      int rl = mt * 16 + c;
      bool v = rl < L;
      if constexpr (XB) {
        const short* xp = (const short*)xsrc + (size_t)(start + (v ? rl : 0)) * HID + g * 8;
        #pragma unroll
        for (int ks = 0; ks < 8; ks++) { bf16x8 t = *(const bf16x8*)(xp + ks * 32); a[ks] = v ? t : zf; }
      } else {
        const float* xp = (const float*)xsrc + (size_t)(start + (v ? rl : 0)) * HID + g * 8;
        #pragma unroll
        for (int ks = 0; ks < 8; ks++) { bf16x8 t = ld_cvt8(xp + ks * 32); a[ks] = v ? t : zf; }
      }
    }

    #pragma unroll
    for (int nt = 0; nt < 12; nt++) {   // 192 output cols: q(0-3) k(4-7) v(8-11)
      // frag-order weight slab for (sec=nt>>2, head, nt&3): 8 x 1KB coalesced chunks
      const short* Wp = Wb + ((size_t)(((nt >> 2) * 4 + head) * 4 + (nt & 3)) << 12) + lane * 8;
      bf16x8 bw[8];
      #pragma unroll
      for (int ks = 0; ks < 8; ks++) bw[ks] = *(const bf16x8*)(Wp + ks * 512);

      f32x4 acc = {0.f, 0.f, 0.f, 0.f};
      if (nt < 4) {                     // Q^T: swap operands, keep Q in registers
        #pragma unroll
        for (int ks = 0; ks < 8; ks++) acc = MFMA16(bw[ks], a[ks], acc);
        #pragma unroll
        for (int r = 0; r < 4; r++) qb[i][nt][r] = f2bf(acc[r] * 0.125f);  // fold DH^-0.5 (exact pow2)
      } else {
        #pragma unroll
        for (int ks = 0; ks < 8; ks++) acc = MFMA16(a[ks], bw[ks], acc);
        #pragma unroll
        for (int r = 0; r < 4; r++) {
          short val = f2bf(acc[r]);
          int row = mt * 16 + g * 4 + r;                  // < Mt*16 always
          if (nt < 8) K_s[row * LQK + (nt - 4) * 16 + c] = val;            // K row-major
          else        V_t[((nt - 8) * 16 + c) * LVT + row] = val;          // V transposed
        }
      }
    }
  }
  __syncthreads();   // uniform: all K_s / V_t visible

  // ================= Phase 2: attention per owned q-tile =================
  #pragma unroll
  for (int i = 0; i < 2; i++) {
    const int mt = wave + 4 * i;
    if (mt >= Mt) continue;

    // ---- S^T = K Q^T: lane(c,g) reg r = S[q=c][key=nt*16+g*4+r] ----
    float sv[8][4];
    #pragma unroll
    for (int nt = 0; nt < 8; nt++) {
      if (nt < Mt) {
        f32x4 acc = {0.f, 0.f, 0.f, 0.f};
        #pragma unroll
        for (int ks = 0; ks < 4; ks++) {
          bf16x4 kb = *(const bf16x4*)&K_s[(nt * 16 + c) * LQK + ks * 16 + g * 4];
          acc = mfma16k(kb, qb[i][ks], acc);
        }
        sv[nt][0] = acc[0]; sv[nt][1] = acc[1]; sv[nt][2] = acc[2]; sv[nt][3] = acc[3];
      }
    }

    // ---- softmax: keys lane-local (nt,r), queries per-lane; cross-g via 2 shfl ----
    float mr = -3.0e38f;
    #pragma unroll
    for (int nt = 0; nt < 8; nt++) {
      if (nt < Mt) {
        #pragma unroll
        for (int r = 0; r < 4; r++) {
          int key = nt * 16 + g * 4 + r;
          float v = (key < L) ? sv[nt][r] : -3.0e38f;
          sv[nt][r] = v;
          mr = fmaxf(mr, v);
        }
      }
    }
    mr = fmaxf(mr, __shfl_xor(mr, 16));
    mr = fmaxf(mr, __shfl_xor(mr, 32));
    float sum = 0.f;
    #pragma unroll
    for (int nt = 0; nt < 8; nt++) {
      if (nt < Mt) {
        #pragma unroll
        for (int r = 0; r < 4; r++) {
          float e = (sv[nt][r] > -1.0e37f) ? __expf(sv[nt][r] - mr) : 0.f;
          sv[nt][r] = e;
          sum += e;
        }
      }
    }
    sum += __shfl_xor(sum, 16);
    sum += __shfl_xor(sum, 32);
    float inv = 1.f / sum;

    bf16x4 pa[8];                       // P A-frags: direct, no cross-lane movement
    #pragma unroll
    for (int nt = 0; nt < 8; nt++) {
      if (nt < Mt) {
        #pragma unroll
        for (int r = 0; r < 4; r++) pa[nt][r] = f2bf(sv[nt][r] * inv);
      }
    }

    // ---- O = P V, ReLU, store bf16 to ws ----
    #pragma unroll
    for (int nt2 = 0; nt2 < 4; nt2++) {
      f32x4 acc = {0.f, 0.f, 0.f, 0.f};
      #pragma unroll
      for (int nt = 0; nt < 8; nt++) {
        if (nt < Mt) {
          bf16x4 vb = *(const bf16x4*)&V_t[(nt2 * 16 + c) * LVT + nt * 16 + g * 4];
          acc = mfma16k(pa[nt], vb, acc);
        }
      }
      #pragma unroll
      for (int r = 0; r < 4; r++) {
        int rl = mt * 16 + g * 4 + r;
        if (rl < L)
          O[(size_t)(start + rl) * HID + head * 64 + nt2 * 16 + c] =
              f2bf(fmaxf(acc[r], 0.f));
      }
    }
  }
}

// MFMA out-projection + bias + LayerNorm. Block = 32 rows, wave owns 64 cols.
// Ob staged through LDS (coalesced global reads); Wo read from frag-order Wb.
__global__ __launch_bounds__(256) void proj_ln_kernel(
    const short* __restrict__ Ob, const short* __restrict__ Wb,
    const float* __restrict__ bo, const float* __restrict__ gamma,
    const float* __restrict__ beta, float* __restrict__ out, int total)
{
  __shared__ __align__(16) float o_s[32 * 260];   // 33.3 KB; ob_s (16.9 KB) aliases it
  short* ob_s = (short*)o_s;                      // [32][264] bf16 staging
  const int base = blockIdx.x * 32;
  const int tid  = threadIdx.x;
  const int wave = tid >> 6;
  const int lane = tid & 63;
  const int c = lane & 15, g = lane >> 4;

  // ---- stage 32 rows of Ob into LDS, coalesced (1024 bf16x8 chunks) ----
  #pragma unroll
  for (int t = 0; t < 4; t++) {
    int q = tid + t * 256;
    int row = q >> 5, cc = q & 31;
    int grow = base + row; if (grow >= total) grow = total - 1;
    *(bf16x8*)&ob_s[row * 264 + cc * 8] = *(const bf16x8*)(Ob + (size_t)grow * HID + cc * 8);
  }
  __syncthreads();

  // A-frags from LDS (2-way max bank aliasing at stride 264)
  bf16x8 a[2][8];
  #pragma unroll
  for (int i = 0; i < 2; i++)
    #pragma unroll
    for (int ks = 0; ks < 8; ks++)
      a[i][ks] = *(const bf16x8*)&ob_s[(i * 16 + c) * 264 + ks * 32 + g * 8];
  __syncthreads();   // ob_s dead; o_s may be written below

  #pragma unroll
  for (int nt = 0; nt < 4; nt++) {
    // frag-order Wo slab (mat=3, h=wave, nt): 8 x 1KB coalesced chunks
    const short* Wp = Wb + ((size_t)((12 + wave) * 4 + nt) << 12) + lane * 8;
    bf16x8 b[8];
    #pragma unroll
    for (int ks = 0; ks < 8; ks++) b[ks] = *(const bf16x8*)(Wp + ks * 512);
    #pragma unroll
    for (int i = 0; i < 2; i++) {
      f32x4 acc = {0.f, 0.f, 0.f, 0.f};
      #pragma unroll
      for (int ks = 0; ks < 8; ks++) acc = MFMA16(a[i][ks], b[ks], acc);
      #pragma unroll
      for (int r = 0; r < 4; r++)
        o_s[(i * 16 + g * 4 + r) * 260 + wave * 64 + nt * 16 + c] = acc[r];
    }
  }
  __syncthreads();

  // LayerNorm: wave handles 8 rows; lane covers 4 cols
  float4 bo4 = *(const float4*)(bo + lane * 4);
  float4 g4  = *(const float4*)(gamma + lane * 4);
  float4 b4  = *(const float4*)(beta + lane * 4);
  #pragma unroll
  for (int r8 = 0; r8 < 8; r8++) {
    int rl = wave * 8 + r8;
    float4 o = *(const float4*)&o_s[rl * 260 + lane * 4];
    o.x += bo4.x; o.y += bo4.y; o.z += bo4.z; o.w += bo4.w;
    float s  = o.x + o.y + o.z + o.w;
    float ss = o.x * o.x + o.y * o.y + o.z * o.z + o.w * o.w;
    #pragma unroll
    for (int off = 32; off; off >>= 1) { s += __shfl_xor(s, off); ss += __shfl_xor(ss, off); }
    float mu  = s * (1.f / HID);
    float var = ss * (1.f / HID) - mu * mu;
    float inv = rsqrtf(var + 1e-5f);
    int row = base + rl;
    if (row < total) {
      float4 res;
      res.x = (o.x - mu) * inv * g4.x + b4.x;
      res.y = (o.y - mu) * inv * g4.y + b4.y;
      res.z = (o.z - mu) * inv * g4.z + b4.z;
      res.w = (o.w - mu) * inv * g4.w + b4.w;
      if (row == 0) res = make_float4(0.f, 0.f, 0.f, 0.f);  // cached_zero_vector
      *(float4*)(out + (size_t)row * HID + lane * 4) = res;
    }
  }
}

extern "C" void kernel_launch(void* const* d_in, const int* in_sizes, int n_in,
                              void* d_out, int out_size, void* d_ws, size_t ws_size,
                              hipStream_t stream) {
  const float* msg   = (const float*)d_in[0];
  const float* Wq    = (const float*)d_in[1];
  const float* Wk    = (const float*)d_in[2];
  const float* Wv    = (const float*)d_in[3];
  const float* Wo    = (const float*)d_in[4];
  const float* bo    = (const float*)d_in[5];
  const float* gamma = (const float*)d_in[6];
  const float* beta  = (const float*)d_in[7];
  const int* starts  = (const int*)d_in[8];
  const int* sizes   = (const int*)d_in[9];

  const int nmols = in_sizes[8];
  const int total = in_sizes[0] / HID;

  short* O  = (short*)d_ws;                       // [total][HID] bf16 o_relu scratch (~84 MB)
  short* Wb = O + (size_t)total * HID;            // 4 x 256x256 bf16 weights, frag order (+512 KB)
  short* Xb = Wb + 4 * HID * HID;                 // [total][HID] bf16 msg (+~84 MB, if it fits)

  size_t need = ((size_t)total * HID * 2 + 4 * HID * HID) * sizeof(short);
  const bool use_xb = ws_size >= need;

  cvt_w_kernel<<<128, 256, 0, stream>>>(Wq, Wk, Wv, Wo, Wb);
  if (use_xb) {
    int n8 = total * (HID / 8);
    int gsz = (n8 + 255) / 256; if (gsz > 2048) gsz = 2048;
    cvt_msg_kernel<<<gsz, 256, 0, stream>>>(msg, Xb, n8);
    attn_kernel<true><<<nmols * NH, 256, 0, stream>>>(Xb, Wb, starts, sizes, O);
  } else {
    attn_kernel<false><<<nmols * NH, 256, 0, stream>>>(msg, Wb, starts, sizes, O);
  }
  proj_ln_kernel<<<(total + 31) / 32, 256, 0, stream>>>(
      O, Wb, bo, gamma, beta, (float*)d_out, total);
}